// Round 2
// baseline (2663.616 us; speedup 1.0000x reference)
//
#include <hip/hip_runtime.h>

#define N_NODES 100000
#define N_EDGES 1600000

// ---------------------------------------------------------------------------
// Edge scatter-add: agg[dst] += feat[src], C channels per node.
// One wave per edge; lanes stride channels (coalesced reads, fp32 atomics).
// ---------------------------------------------------------------------------
__global__ __launch_bounds__(256) void scatter_add_k(
    const float* __restrict__ feat, const int* __restrict__ src,
    const int* __restrict__ dst, float* __restrict__ agg, int nE, int C) {
  int lane = threadIdx.x & 63;
  int wave = (int)((blockIdx.x * blockDim.x + threadIdx.x) >> 6);
  int nw   = (int)((gridDim.x * blockDim.x) >> 6);
  for (int e = wave; e < nE; e += nw) {
    int s = src[e];
    int d = dst[e];
    const float* fs = feat + (long)s * C;
    float*       ad = agg  + (long)d * C;
    for (int c = lane; c < C; c += 64) {
      atomicAdd(&ad[c], fs[c]);
    }
  }
}

// ---------------------------------------------------------------------------
// Tiled fp32 GEMM: out[M,N] = act( A_eff[M,K] @ W[K,N] + bias[N] )
//   FUSE_IN: A_eff = (1+eps)*X + AGG   (GIN input fusion)
// BM=BN=64, BK=16, 256 threads, 4x4 micro-tile per thread.
// ---------------------------------------------------------------------------
template <bool FUSE_IN, bool RELU>
__global__ __launch_bounds__(256) void gemm_k(
    const float* __restrict__ X, const float* __restrict__ AGG,
    const float* __restrict__ epsp, const float* __restrict__ W,
    const float* __restrict__ bias, float* __restrict__ out,
    int M, int K, int N) {
  constexpr int BM = 64, BN = 64, BK = 16;
  __shared__ __align__(16) float As[BK][BM + 4];
  __shared__ __align__(16) float Bs[BK][BN + 4];

  const int tid = threadIdx.x;
  const int tx = tid & 15;
  const int ty = tid >> 4;
  const int m0 = blockIdx.x * BM;
  const int n0 = blockIdx.y * BN;

  float s = 1.0f;
  if constexpr (FUSE_IN) s = 1.0f + epsp[0];

  float acc[4][4] = {};

  const int a_m = tid >> 2;
  const int a_k = (tid & 3) * 4;
  const int b_k = tid >> 4;
  const int b_n = (tid & 15) * 4;

  for (int k0 = 0; k0 < K; k0 += BK) {
    const int gm = m0 + a_m;
    float4 av = make_float4(0.f, 0.f, 0.f, 0.f);
    if (gm < M) {
      av = *reinterpret_cast<const float4*>(X + (long)gm * K + k0 + a_k);
      if constexpr (FUSE_IN) {
        float4 g = *reinterpret_cast<const float4*>(AGG + (long)gm * K + k0 + a_k);
        av.x = fmaf(av.x, s, g.x);
        av.y = fmaf(av.y, s, g.y);
        av.z = fmaf(av.z, s, g.z);
        av.w = fmaf(av.w, s, g.w);
      }
    }
    As[a_k + 0][a_m] = av.x;
    As[a_k + 1][a_m] = av.y;
    As[a_k + 2][a_m] = av.z;
    As[a_k + 3][a_m] = av.w;

    float4 bv = *reinterpret_cast<const float4*>(W + (long)(k0 + b_k) * N + n0 + b_n);
    *reinterpret_cast<float4*>(&Bs[b_k][b_n]) = bv;

    __syncthreads();

#pragma unroll
    for (int kk = 0; kk < BK; ++kk) {
      float4 a4 = *reinterpret_cast<const float4*>(&As[kk][ty * 4]);
      float4 b4 = *reinterpret_cast<const float4*>(&Bs[kk][tx * 4]);
      float aa[4] = {a4.x, a4.y, a4.z, a4.w};
      float bb[4] = {b4.x, b4.y, b4.z, b4.w};
#pragma unroll
      for (int i = 0; i < 4; ++i)
#pragma unroll
        for (int j = 0; j < 4; ++j)
          acc[i][j] = fmaf(aa[i], bb[j], acc[i][j]);
    }
    __syncthreads();
  }

  float4 bb4 = *reinterpret_cast<const float4*>(&bias[n0 + tx * 4]);
  float bsv[4] = {bb4.x, bb4.y, bb4.z, bb4.w};
#pragma unroll
  for (int i = 0; i < 4; ++i) {
    int gm = m0 + ty * 4 + i;
    if (gm < M) {
      float v[4];
#pragma unroll
      for (int j = 0; j < 4; ++j) {
        v[j] = acc[i][j] + bsv[j];
        if constexpr (RELU) v[j] = fmaxf(v[j], 0.0f);
      }
      *reinterpret_cast<float4*>(&out[(long)gm * N + n0 + tx * 4]) =
          make_float4(v[0], v[1], v[2], v[3]);
    }
  }
}

// ---------------------------------------------------------------------------
// Fused GIN MLP (layer 2): out = ((1+eps)X + AGG) @ Wa + ba |> relu |> @ Wb + bb
// BM=32 rows/block, hidden tile (32 x HID) held in LDS between the two GEMMs.
// Static LDS: As 2.3KB + Hs 33.3KB + Was 16.6KB + Wbs 8.4KB = 60.7KB < 64KB.
// ---------------------------------------------------------------------------
template <int K, int HID, int NOUT, bool RELU_OUT>
__global__ __launch_bounds__(256) void gin_mlp_fused_k(
    const float* __restrict__ X, const float* __restrict__ AGG,
    const float* __restrict__ epsp,
    const float* __restrict__ Wa, const float* __restrict__ ba,
    const float* __restrict__ Wb, const float* __restrict__ bb,
    float* __restrict__ out, int M) {
  constexpr int BM = 32, BK = 16;
  __shared__ __align__(16) float As[BK][BM + 4];
  __shared__ __align__(16) float Hs[BM][HID + 4];
  __shared__ __align__(16) float Was[BK][HID + 4];
  __shared__ __align__(16) float Wbs[BK][NOUT + 4];

  const int tid = threadIdx.x;
  const int m0 = blockIdx.x * BM;
  const float s = 1.0f + epsp[0];

  const int r0 = (tid >> 5) * 4;     // row base: 0,4,...,28
  const int c1 = (tid & 31) * 8;     // stage-1 col base: 0..248

  // ---------------- stage 1: H = relu(((1+eps)X + AGG) @ Wa + ba) ----------
  float acc[4][8] = {};

  for (int k0 = 0; k0 < K; k0 += BK) {
    if (tid < 128) {                 // A tile (transposed into LDS)
      int r = tid >> 2, kq = (tid & 3) * 4;
      int gm = m0 + r;
      float4 av = make_float4(0.f, 0.f, 0.f, 0.f);
      if (gm < M) {
        av = *reinterpret_cast<const float4*>(X + (long)gm * K + k0 + kq);
        float4 g = *reinterpret_cast<const float4*>(AGG + (long)gm * K + k0 + kq);
        av.x = fmaf(av.x, s, g.x);
        av.y = fmaf(av.y, s, g.y);
        av.z = fmaf(av.z, s, g.z);
        av.w = fmaf(av.w, s, g.w);
      }
      As[kq + 0][r] = av.x;
      As[kq + 1][r] = av.y;
      As[kq + 2][r] = av.z;
      As[kq + 3][r] = av.w;
    }
    {                                // Wa tile: 16 x HID
      int kr = tid >> 4, f = tid & 15;
#pragma unroll
      for (int u = 0; u < HID / 64; ++u) {
        int n4 = (f + 16 * u) << 2;
        *reinterpret_cast<float4*>(&Was[kr][n4]) =
            *reinterpret_cast<const float4*>(&Wa[(long)(k0 + kr) * HID + n4]);
      }
    }
    __syncthreads();
#pragma unroll
    for (int kk = 0; kk < BK; ++kk) {
      float a[4];
#pragma unroll
      for (int i = 0; i < 4; ++i) a[i] = As[kk][r0 + i];
      float4 b0 = *reinterpret_cast<const float4*>(&Was[kk][c1]);
      float4 b1 = *reinterpret_cast<const float4*>(&Was[kk][c1 + 4]);
      float b[8] = {b0.x, b0.y, b0.z, b0.w, b1.x, b1.y, b1.z, b1.w};
#pragma unroll
      for (int i = 0; i < 4; ++i)
#pragma unroll
        for (int j = 0; j < 8; ++j)
          acc[i][j] = fmaf(a[i], b[j], acc[i][j]);
    }
    __syncthreads();
  }

  {  // bias + relu -> Hs
    float4 q0 = *reinterpret_cast<const float4*>(&ba[c1]);
    float4 q1 = *reinterpret_cast<const float4*>(&ba[c1 + 4]);
    float bv[8] = {q0.x, q0.y, q0.z, q0.w, q1.x, q1.y, q1.z, q1.w};
#pragma unroll
    for (int i = 0; i < 4; ++i) {
      float v[8];
#pragma unroll
      for (int j = 0; j < 8; ++j) v[j] = fmaxf(acc[i][j] + bv[j], 0.0f);
      *reinterpret_cast<float4*>(&Hs[r0 + i][c1]) = make_float4(v[0], v[1], v[2], v[3]);
      *reinterpret_cast<float4*>(&Hs[r0 + i][c1 + 4]) = make_float4(v[4], v[5], v[6], v[7]);
    }
  }
  __syncthreads();

  // ---------------- stage 2: out = H @ Wb + bb -----------------------------
  const int c2 = (tid & 31) * 4;     // 0..124 (NOUT=128)
  float acc2[4][4] = {};

  for (int k0 = 0; k0 < HID; k0 += BK) {
    {                                // Wb tile: 16 x NOUT
      int kr = tid >> 4, f = tid & 15;
#pragma unroll
      for (int u = 0; u < NOUT / 64; ++u) {
        int n4 = (f + 16 * u) << 2;
        *reinterpret_cast<float4*>(&Wbs[kr][n4]) =
            *reinterpret_cast<const float4*>(&Wb[(long)(k0 + kr) * NOUT + n4]);
      }
    }
    __syncthreads();
#pragma unroll
    for (int kk = 0; kk < BK; ++kk) {
      float a[4];
#pragma unroll
      for (int i = 0; i < 4; ++i) a[i] = Hs[r0 + i][k0 + kk];
      float4 b4 = *reinterpret_cast<const float4*>(&Wbs[kk][c2]);
      float b[4] = {b4.x, b4.y, b4.z, b4.w};
#pragma unroll
      for (int i = 0; i < 4; ++i)
#pragma unroll
        for (int j = 0; j < 4; ++j)
          acc2[i][j] = fmaf(a[i], b[j], acc2[i][j]);
    }
    __syncthreads();
  }

  float4 bb4 = *reinterpret_cast<const float4*>(&bb[c2]);
  float bsv[4] = {bb4.x, bb4.y, bb4.z, bb4.w};
#pragma unroll
  for (int i = 0; i < 4; ++i) {
    int gm = m0 + r0 + i;
    if (gm < M) {
      float v[4];
#pragma unroll
      for (int j = 0; j < 4; ++j) {
        v[j] = acc2[i][j] + bsv[j];
        if constexpr (RELU_OUT) v[j] = fmaxf(v[j], 0.0f);
      }
      *reinterpret_cast<float4*>(&out[(long)gm * NOUT + c2]) =
          make_float4(v[0], v[1], v[2], v[3]);
    }
  }
}

extern "C" void kernel_launch(void* const* d_in, const int* in_sizes, int n_in,
                              void* d_out, int out_size, void* d_ws, size_t ws_size,
                              hipStream_t stream) {
  const float* x    = (const float*)d_in[0];
  const int*   ei   = (const int*)d_in[1];
  const float* eps1 = (const float*)d_in[2];
  const float* W1a  = (const float*)d_in[3];
  const float* b1a  = (const float*)d_in[4];
  const float* W1b  = (const float*)d_in[5];
  const float* b1b  = (const float*)d_in[6];
  const float* eps2 = (const float*)d_in[7];
  const float* W2a  = (const float*)d_in[8];
  const float* b2a  = (const float*)d_in[9];
  const float* W2b  = (const float*)d_in[10];
  const float* b2b  = (const float*)d_in[11];
  float* out = (float*)d_out;

  const int* srcp = ei;
  const int* dstp = ei + N_EDGES;

  // Workspace: TWO N*256 fp32 buffers (204.8 MB peak).
  //   B1: agg1 (128ch) -> h (256ch)
  //   B2: t1 (256ch)   -> agg2 (256ch)
  char* ws = (char*)d_ws;
  const size_t SZ = (size_t)N_NODES * 256 * sizeof(float);
  float* B1 = (float*)(ws);
  float* B2 = (float*)(ws + SZ);

  dim3 blk(256);
  dim3 gScatter(8192);
  dim3 g256((N_NODES + 63) / 64, 256 / 64);
  dim3 gFused((N_NODES + 31) / 32);

  // ---------------- Layer 1 ----------------
  hipMemsetAsync(B1, 0, (size_t)N_NODES * 128 * sizeof(float), stream);
  scatter_add_k<<<gScatter, blk, 0, stream>>>(x, srcp, dstp, B1, N_EDGES, 128);
  // t1(B2) = relu(((1+eps1)x + agg1) @ W1a + b1a)   [K=128, N=256]
  gemm_k<true, true><<<g256, blk, 0, stream>>>(x, B1, eps1, W1a, b1a, B2,
                                               N_NODES, 128, 256);
  // h(B1) = relu(t1 @ W1b + b1b)   (conv-out + inter-layer relu fused)
  gemm_k<false, true><<<g256, blk, 0, stream>>>(B2, nullptr, nullptr, W1b, b1b, B1,
                                                N_NODES, 256, 256);

  // ---------------- Layer 2 (fused MLP) ----------------
  hipMemsetAsync(B2, 0, (size_t)N_NODES * 256 * sizeof(float), stream);
  scatter_add_k<<<gScatter, blk, 0, stream>>>(B1, srcp, dstp, B2, N_EDGES, 256);
  // out = ((1+eps2)h + agg2) @ W2a + b2a |> relu |> @ W2b + b2b
  gin_mlp_fused_k<256, 256, 128, false><<<gFused, blk, 0, stream>>>(
      B1, B2, eps2, W2a, b2a, W2b, b2b, out, N_NODES);
}

// Round 3
// 1419.383 us; speedup vs baseline: 1.8766x; 1.8766x over previous
//
#include <hip/hip_runtime.h>

#define N_NODES 100000
#define N_EDGES 1600000

// ===========================================================================
// CSR build (rebuilt every call — same work each call, graph-capture safe).
// Scratch lives in d_out (dead until the final fused-MLP write).
// ===========================================================================
__global__ __launch_bounds__(256) void hist_k(const int* __restrict__ dst,
                                              int* __restrict__ deg, int nE) {
  int i = blockIdx.x * blockDim.x + threadIdx.x;
  if (i < nE) atomicAdd(&deg[dst[i]], 1);
}

// Single-workgroup exclusive scan: deg[0..n) -> rowStart[0..n)
__global__ __launch_bounds__(1024) void scan_k(const int* __restrict__ deg,
                                               int* __restrict__ rowStart, int n) {
  __shared__ int part[1024];
  const int tid = threadIdx.x;
  const int chunk = (n + 1023) >> 10;
  const int base = tid * chunk;
  const int end = min(base + chunk, n);
  int s = 0;
  for (int i = base; i < end; ++i) s += deg[i];
  part[tid] = s;
  __syncthreads();
  for (int off = 1; off < 1024; off <<= 1) {
    int v = (tid >= off) ? part[tid - off] : 0;
    __syncthreads();
    part[tid] += v;
    __syncthreads();
  }
  int run = part[tid] - s;  // exclusive offset for this chunk
  for (int i = base; i < end; ++i) {
    rowStart[i] = run;
    run += deg[i];
  }
}

// Permute src ids into dst-sorted order. cursor==rowStart (mutated to rowEnd).
__global__ __launch_bounds__(256) void fill_k(const int* __restrict__ src,
                                              const int* __restrict__ dst,
                                              int* __restrict__ cursor,
                                              int* __restrict__ sortedSrc, int nE) {
  int i = blockIdx.x * blockDim.x + threadIdx.x;
  if (i < nE) {
    int p = atomicAdd(&cursor[dst[i]], 1);
    sortedSrc[p] = src[i];
  }
}

// ===========================================================================
// CSR gather-sum aggregation, fused with GIN combine:
//   out[n] = (1+eps) * x[n] + sum_{e in-edges(n)} feat[src[e]]
// One wave per node; lane holds C/64 channels (float2 for C=128, float4 for 256).
// rowEnd[n] is the post-fill cursor (= exclusive start of n+1).
// ===========================================================================
template <int C>
__global__ __launch_bounds__(256) void agg_k(
    const float* __restrict__ feat, const float* __restrict__ xin,
    const float* __restrict__ epsp, const int* __restrict__ rowEnd,
    const int* __restrict__ sortedSrc, float* __restrict__ outc, int M) {
  constexpr int V = C / 64;  // floats per lane
  const int lane = threadIdx.x & 63;
  const int w = (int)((blockIdx.x * blockDim.x + threadIdx.x) >> 6);
  if (w >= M) return;
  const int start = w ? rowEnd[w - 1] : 0;
  const int end = rowEnd[w];
  const int c0 = lane * V;

  float acc[V] = {};
  int e = start;
  // 4-wide unroll: 4 independent row loads in flight
  for (; e + 4 <= end; e += 4) {
    int s0 = sortedSrc[e + 0];
    int s1 = sortedSrc[e + 1];
    int s2 = sortedSrc[e + 2];
    int s3 = sortedSrc[e + 3];
    const float* r0 = feat + (long)s0 * C + c0;
    const float* r1 = feat + (long)s1 * C + c0;
    const float* r2 = feat + (long)s2 * C + c0;
    const float* r3 = feat + (long)s3 * C + c0;
    if constexpr (V == 4) {
      float4 a = *(const float4*)r0, b = *(const float4*)r1;
      float4 c = *(const float4*)r2, d = *(const float4*)r3;
      acc[0] += a.x + b.x + c.x + d.x;
      acc[1] += a.y + b.y + c.y + d.y;
      acc[2] += a.z + b.z + c.z + d.z;
      acc[3] += a.w + b.w + c.w + d.w;
    } else {
      float2 a = *(const float2*)r0, b = *(const float2*)r1;
      float2 c = *(const float2*)r2, d = *(const float2*)r3;
      acc[0] += a.x + b.x + c.x + d.x;
      acc[1] += a.y + b.y + c.y + d.y;
    }
  }
  for (; e < end; ++e) {
    const float* r = feat + (long)sortedSrc[e] * C + c0;
    if constexpr (V == 4) {
      float4 a = *(const float4*)r;
      acc[0] += a.x; acc[1] += a.y; acc[2] += a.z; acc[3] += a.w;
    } else {
      float2 a = *(const float2*)r;
      acc[0] += a.x; acc[1] += a.y;
    }
  }

  const float s = 1.0f + epsp[0];
  const float* xr = xin + (long)w * C + c0;
  float* orow = outc + (long)w * C + c0;
  if constexpr (V == 4) {
    float4 xv = *(const float4*)xr;
    *(float4*)orow = make_float4(fmaf(s, xv.x, acc[0]), fmaf(s, xv.y, acc[1]),
                                 fmaf(s, xv.z, acc[2]), fmaf(s, xv.w, acc[3]));
  } else {
    float2 xv = *(const float2*)xr;
    *(float2*)orow = make_float2(fmaf(s, xv.x, acc[0]), fmaf(s, xv.y, acc[1]));
  }
}

// ===========================================================================
// Tiled fp32 GEMM: out = act(A[M,K] @ W[K,N] + bias)
// BM=BN=64, BK=16, 256 threads, 4x4 micro-tile.
// ===========================================================================
template <bool RELU>
__global__ __launch_bounds__(256) void gemm_k(
    const float* __restrict__ A, const float* __restrict__ W,
    const float* __restrict__ bias, float* __restrict__ out,
    int M, int K, int N) {
  constexpr int BM = 64, BN = 64, BK = 16;
  __shared__ __align__(16) float As[BK][BM + 4];
  __shared__ __align__(16) float Bs[BK][BN + 4];

  const int tid = threadIdx.x;
  const int tx = tid & 15;
  const int ty = tid >> 4;
  const int m0 = blockIdx.x * BM;
  const int n0 = blockIdx.y * BN;

  float acc[4][4] = {};

  const int a_m = tid >> 2;
  const int a_k = (tid & 3) * 4;
  const int b_k = tid >> 4;
  const int b_n = (tid & 15) * 4;

  for (int k0 = 0; k0 < K; k0 += BK) {
    const int gm = m0 + a_m;
    float4 av = make_float4(0.f, 0.f, 0.f, 0.f);
    if (gm < M) av = *reinterpret_cast<const float4*>(A + (long)gm * K + k0 + a_k);
    As[a_k + 0][a_m] = av.x;
    As[a_k + 1][a_m] = av.y;
    As[a_k + 2][a_m] = av.z;
    As[a_k + 3][a_m] = av.w;

    *reinterpret_cast<float4*>(&Bs[b_k][b_n]) =
        *reinterpret_cast<const float4*>(W + (long)(k0 + b_k) * N + n0 + b_n);
    __syncthreads();

#pragma unroll
    for (int kk = 0; kk < BK; ++kk) {
      float4 a4 = *reinterpret_cast<const float4*>(&As[kk][ty * 4]);
      float4 b4 = *reinterpret_cast<const float4*>(&Bs[kk][tx * 4]);
      float aa[4] = {a4.x, a4.y, a4.z, a4.w};
      float bb[4] = {b4.x, b4.y, b4.z, b4.w};
#pragma unroll
      for (int i = 0; i < 4; ++i)
#pragma unroll
        for (int j = 0; j < 4; ++j)
          acc[i][j] = fmaf(aa[i], bb[j], acc[i][j]);
    }
    __syncthreads();
  }

  float4 bb4 = *reinterpret_cast<const float4*>(&bias[n0 + tx * 4]);
  float bsv[4] = {bb4.x, bb4.y, bb4.z, bb4.w};
#pragma unroll
  for (int i = 0; i < 4; ++i) {
    int gm = m0 + ty * 4 + i;
    if (gm < M) {
      float v[4];
#pragma unroll
      for (int j = 0; j < 4; ++j) {
        v[j] = acc[i][j] + bsv[j];
        if constexpr (RELU) v[j] = fmaxf(v[j], 0.0f);
      }
      *reinterpret_cast<float4*>(&out[(long)gm * N + n0 + tx * 4]) =
          make_float4(v[0], v[1], v[2], v[3]);
    }
  }
}

// ===========================================================================
// Fused layer-2 MLP: out = relu(A @ Wa + ba) @ Wb + bb
// A is the pre-combined GIN input. 32 rows/block; hidden tile in LDS.
// ===========================================================================
template <int K, int HID, int NOUT>
__global__ __launch_bounds__(256) void gin_mlp_fused_k(
    const float* __restrict__ A,
    const float* __restrict__ Wa, const float* __restrict__ ba,
    const float* __restrict__ Wb, const float* __restrict__ bb,
    float* __restrict__ out, int M) {
  constexpr int BM = 32, BK = 16;
  __shared__ __align__(16) float As[BK][BM + 4];
  __shared__ __align__(16) float Hs[BM][HID + 4];
  __shared__ __align__(16) float Was[BK][HID + 4];
  __shared__ __align__(16) float Wbs[BK][NOUT + 4];

  const int tid = threadIdx.x;
  const int m0 = blockIdx.x * BM;

  const int r0 = (tid >> 5) * 4;
  const int c1 = (tid & 31) * 8;

  float acc[4][8] = {};
  for (int k0 = 0; k0 < K; k0 += BK) {
    if (tid < 128) {
      int r = tid >> 2, kq = (tid & 3) * 4;
      int gm = m0 + r;
      float4 av = make_float4(0.f, 0.f, 0.f, 0.f);
      if (gm < M) av = *reinterpret_cast<const float4*>(A + (long)gm * K + k0 + kq);
      As[kq + 0][r] = av.x;
      As[kq + 1][r] = av.y;
      As[kq + 2][r] = av.z;
      As[kq + 3][r] = av.w;
    }
    {
      int kr = tid >> 4, f = tid & 15;
#pragma unroll
      for (int u = 0; u < HID / 64; ++u) {
        int n4 = (f + 16 * u) << 2;
        *reinterpret_cast<float4*>(&Was[kr][n4]) =
            *reinterpret_cast<const float4*>(&Wa[(long)(k0 + kr) * HID + n4]);
      }
    }
    __syncthreads();
#pragma unroll
    for (int kk = 0; kk < BK; ++kk) {
      float a[4];
#pragma unroll
      for (int i = 0; i < 4; ++i) a[i] = As[kk][r0 + i];
      float4 b0 = *reinterpret_cast<const float4*>(&Was[kk][c1]);
      float4 b1 = *reinterpret_cast<const float4*>(&Was[kk][c1 + 4]);
      float b[8] = {b0.x, b0.y, b0.z, b0.w, b1.x, b1.y, b1.z, b1.w};
#pragma unroll
      for (int i = 0; i < 4; ++i)
#pragma unroll
        for (int j = 0; j < 8; ++j)
          acc[i][j] = fmaf(a[i], b[j], acc[i][j]);
    }
    __syncthreads();
  }

  {
    float4 q0 = *reinterpret_cast<const float4*>(&ba[c1]);
    float4 q1 = *reinterpret_cast<const float4*>(&ba[c1 + 4]);
    float bv[8] = {q0.x, q0.y, q0.z, q0.w, q1.x, q1.y, q1.z, q1.w};
#pragma unroll
    for (int i = 0; i < 4; ++i) {
      float v[8];
#pragma unroll
      for (int j = 0; j < 8; ++j) v[j] = fmaxf(acc[i][j] + bv[j], 0.0f);
      *reinterpret_cast<float4*>(&Hs[r0 + i][c1]) = make_float4(v[0], v[1], v[2], v[3]);
      *reinterpret_cast<float4*>(&Hs[r0 + i][c1 + 4]) = make_float4(v[4], v[5], v[6], v[7]);
    }
  }
  __syncthreads();

  const int c2 = (tid & 31) * 4;
  float acc2[4][4] = {};
  for (int k0 = 0; k0 < HID; k0 += BK) {
    {
      int kr = tid >> 4, f = tid & 15;
#pragma unroll
      for (int u = 0; u < NOUT / 64; ++u) {
        int n4 = (f + 16 * u) << 2;
        *reinterpret_cast<float4*>(&Wbs[kr][n4]) =
            *reinterpret_cast<const float4*>(&Wb[(long)(k0 + kr) * NOUT + n4]);
      }
    }
    __syncthreads();
#pragma unroll
    for (int kk = 0; kk < BK; ++kk) {
      float a[4];
#pragma unroll
      for (int i = 0; i < 4; ++i) a[i] = Hs[r0 + i][k0 + kk];
      float4 b4 = *reinterpret_cast<const float4*>(&Wbs[kk][c2]);
      float b[4] = {b4.x, b4.y, b4.z, b4.w};
#pragma unroll
      for (int i = 0; i < 4; ++i)
#pragma unroll
        for (int j = 0; j < 4; ++j)
          acc2[i][j] = fmaf(a[i], b[j], acc2[i][j]);
    }
    __syncthreads();
  }

  float4 bb4 = *reinterpret_cast<const float4*>(&bb[c2]);
  float bsv[4] = {bb4.x, bb4.y, bb4.z, bb4.w};
#pragma unroll
  for (int i = 0; i < 4; ++i) {
    int gm = m0 + r0 + i;
    if (gm < M) {
      float v[4];
#pragma unroll
      for (int j = 0; j < 4; ++j) v[j] = acc2[i][j] + bsv[j];
      *reinterpret_cast<float4*>(&out[(long)gm * NOUT + c2]) =
          make_float4(v[0], v[1], v[2], v[3]);
    }
  }
}

extern "C" void kernel_launch(void* const* d_in, const int* in_sizes, int n_in,
                              void* d_out, int out_size, void* d_ws, size_t ws_size,
                              hipStream_t stream) {
  const float* x    = (const float*)d_in[0];
  const int*   ei   = (const int*)d_in[1];
  const float* eps1 = (const float*)d_in[2];
  const float* W1a  = (const float*)d_in[3];
  const float* b1a  = (const float*)d_in[4];
  const float* W1b  = (const float*)d_in[5];
  const float* b1b  = (const float*)d_in[6];
  const float* eps2 = (const float*)d_in[7];
  const float* W2a  = (const float*)d_in[8];
  const float* b2a  = (const float*)d_in[9];
  const float* W2b  = (const float*)d_in[10];
  const float* b2b  = (const float*)d_in[11];
  float* out = (float*)d_out;

  const int* srcp = ei;
  const int* dstp = ei + N_EDGES;

  // Workspace: two N*256 fp32 buffers (204.8 MB — proven to fit).
  char* ws = (char*)d_ws;
  const size_t SZ = (size_t)N_NODES * 256 * sizeof(float);
  float* B1 = (float*)(ws);          // combined1 (128ch) -> h (256ch)
  float* B2 = (float*)(ws + SZ);     // t1 (256ch) -> combined2 (256ch)

  // CSR scratch in d_out (dead until the final fused-MLP write; 7.2MB < 51.2MB)
  char* ob = (char*)d_out;
  int* deg       = (int*)(ob);                       // 400 KB
  int* rowStart  = (int*)(ob + 400 * 1024);          // 400 KB (becomes rowEnd)
  int* sortedSrc = (int*)(ob + 800 * 1024);          // 6.4 MB

  dim3 blk(256);
  dim3 gEdges((N_EDGES + 255) / 256);
  dim3 gAgg((N_NODES + 3) / 4);                      // 1 wave per node
  dim3 g256((N_NODES + 63) / 64, 256 / 64);
  dim3 gFused((N_NODES + 31) / 32);

  // ---- CSR build (once per call) ----
  hipMemsetAsync(deg, 0, N_NODES * sizeof(int), stream);
  hist_k<<<gEdges, blk, 0, stream>>>(dstp, deg, N_EDGES);
  scan_k<<<1, 1024, 0, stream>>>(deg, rowStart, N_NODES);
  fill_k<<<gEdges, blk, 0, stream>>>(srcp, dstp, rowStart, sortedSrc, N_EDGES);
  // rowStart is now rowEnd.

  // ---- Layer 1 ----
  agg_k<128><<<gAgg, blk, 0, stream>>>(x, x, eps1, rowStart, sortedSrc, B1, N_NODES);
  gemm_k<true><<<g256, blk, 0, stream>>>(B1, W1a, b1a, B2, N_NODES, 128, 256);   // t1
  gemm_k<true><<<g256, blk, 0, stream>>>(B2, W1b, b1b, B1, N_NODES, 256, 256);   // h (+relu)

  // ---- Layer 2 ----
  agg_k<256><<<gAgg, blk, 0, stream>>>(B1, B1, eps2, rowStart, sortedSrc, B2, N_NODES);
  gin_mlp_fused_k<256, 256, 128><<<gFused, blk, 0, stream>>>(
      B2, W2a, b2a, W2b, b2b, out, N_NODES);
}

// Round 4
// 1153.824 us; speedup vs baseline: 2.3085x; 1.2302x over previous
//
#include <hip/hip_runtime.h>

#define N_NODES 100000
#define N_EDGES 1600000

typedef __attribute__((ext_vector_type(8))) short short8;
typedef __attribute__((ext_vector_type(4))) float float4e;

// ---------------------------------------------------------------------------
// bf16 split helpers (RNE)
// ---------------------------------------------------------------------------
__device__ __forceinline__ unsigned short f2bf(float f) {
  unsigned u = __float_as_uint(f);
  u += 0x7FFFu + ((u >> 16) & 1u);
  return (unsigned short)(u >> 16);
}
__device__ __forceinline__ float bf2f(unsigned short h) {
  return __uint_as_float(((unsigned)h) << 16);
}
__device__ __forceinline__ unsigned pack2(unsigned short a, unsigned short b) {
  return (unsigned)a | ((unsigned)b << 16);
}

// ===========================================================================
// CSR build (rebuilt every call; scratch lives in d_out, dead by final GEMM).
// ===========================================================================
__global__ __launch_bounds__(256) void hist_k(const int* __restrict__ dst,
                                              int* __restrict__ deg, int nE) {
  int i = blockIdx.x * blockDim.x + threadIdx.x;
  if (i < nE) atomicAdd(&deg[dst[i]], 1);
}

__global__ __launch_bounds__(1024) void scan_k(const int* __restrict__ deg,
                                               int* __restrict__ rowStart, int n) {
  __shared__ int part[1024];
  const int tid = threadIdx.x;
  const int chunk = (n + 1023) >> 10;
  const int base = tid * chunk;
  const int end = min(base + chunk, n);
  int s = 0;
  for (int i = base; i < end; ++i) s += deg[i];
  part[tid] = s;
  __syncthreads();
  for (int off = 1; off < 1024; off <<= 1) {
    int v = (tid >= off) ? part[tid - off] : 0;
    __syncthreads();
    part[tid] += v;
    __syncthreads();
  }
  int run = part[tid] - s;
  for (int i = base; i < end; ++i) {
    rowStart[i] = run;
    run += deg[i];
  }
}

__global__ __launch_bounds__(256) void fill_k(const int* __restrict__ src,
                                              const int* __restrict__ dst,
                                              int* __restrict__ cursor,
                                              int* __restrict__ sortedSrc, int nE) {
  int i = blockIdx.x * blockDim.x + threadIdx.x;
  if (i < nE) {
    int p = atomicAdd(&cursor[dst[i]], 1);
    sortedSrc[p] = src[i];
  }
}

// ===========================================================================
// CSR gather-sum + GIN combine: out[n] = (1+eps)*x[n] + sum_{in-edges} feat[src]
// One wave per node; lane holds C/64 channels.
// ===========================================================================
template <int C>
__global__ __launch_bounds__(256) void agg_k(
    const float* __restrict__ feat, const float* __restrict__ xin,
    const float* __restrict__ epsp, const int* __restrict__ rowEnd,
    const int* __restrict__ sortedSrc, float* __restrict__ outc, int M) {
  constexpr int V = C / 64;
  const int lane = threadIdx.x & 63;
  const int w = (int)((blockIdx.x * blockDim.x + threadIdx.x) >> 6);
  if (w >= M) return;
  const int start = w ? rowEnd[w - 1] : 0;
  const int end = rowEnd[w];
  const int c0 = lane * V;

  float acc[V] = {};
  int e = start;
  for (; e + 4 <= end; e += 4) {
    int s0 = sortedSrc[e + 0];
    int s1 = sortedSrc[e + 1];
    int s2 = sortedSrc[e + 2];
    int s3 = sortedSrc[e + 3];
    const float* r0 = feat + (long)s0 * C + c0;
    const float* r1 = feat + (long)s1 * C + c0;
    const float* r2 = feat + (long)s2 * C + c0;
    const float* r3 = feat + (long)s3 * C + c0;
    if constexpr (V == 4) {
      float4 a = *(const float4*)r0, b = *(const float4*)r1;
      float4 c = *(const float4*)r2, d = *(const float4*)r3;
      acc[0] += a.x + b.x + c.x + d.x;
      acc[1] += a.y + b.y + c.y + d.y;
      acc[2] += a.z + b.z + c.z + d.z;
      acc[3] += a.w + b.w + c.w + d.w;
    } else {
      float2 a = *(const float2*)r0, b = *(const float2*)r1;
      float2 c = *(const float2*)r2, d = *(const float2*)r3;
      acc[0] += a.x + b.x + c.x + d.x;
      acc[1] += a.y + b.y + c.y + d.y;
    }
  }
  for (; e < end; ++e) {
    const float* r = feat + (long)sortedSrc[e] * C + c0;
    if constexpr (V == 4) {
      float4 a = *(const float4*)r;
      acc[0] += a.x; acc[1] += a.y; acc[2] += a.z; acc[3] += a.w;
    } else {
      float2 a = *(const float2*)r;
      acc[0] += a.x; acc[1] += a.y;
    }
  }

  const float s = 1.0f + epsp[0];
  const float* xr = xin + (long)w * C + c0;
  float* orow = outc + (long)w * C + c0;
  if constexpr (V == 4) {
    float4 xv = *(const float4*)xr;
    *(float4*)orow = make_float4(fmaf(s, xv.x, acc[0]), fmaf(s, xv.y, acc[1]),
                                 fmaf(s, xv.z, acc[2]), fmaf(s, xv.w, acc[3]));
  } else {
    float2 xv = *(const float2*)xr;
    *(float2*)orow = make_float2(fmaf(s, xv.x, acc[0]), fmaf(s, xv.y, acc[1]));
  }
}

// ===========================================================================
// Split-bf16 MFMA GEMM: out = act(A[M,K] @ W[K,N] + bias)
//   A = A_hi + A_lo, W = W_hi + W_lo (bf16 each); 3 MFMA passes, fp32 acc.
// 128x128 tile, BK=32, 4 waves, 4x4 frags of mfma_f32_16x16x32_bf16 per wave.
// LDS: A row-major [m][k] (+8 pad), W transposed [n][k] (+8 pad): all frag
// reads are contiguous ds_read_b128 with 2-way (free) bank aliasing.
// ===========================================================================
template <bool RELU>
__global__ __launch_bounds__(256) void gemm_bf16s_k(
    const float* __restrict__ A, const float* __restrict__ W,
    const float* __restrict__ bias, float* __restrict__ out,
    int M, int K, int N) {
  __shared__ __align__(16) short Ah[128][40];
  __shared__ __align__(16) short Al[128][40];
  __shared__ __align__(16) short Bh[128][40];
  __shared__ __align__(16) short Bl[128][40];

  const int tid = threadIdx.x;
  const int lane = tid & 63;
  const int wave = tid >> 6;
  const int wmi = wave >> 1;        // 0..1 : 64-row slab
  const int wni = wave & 1;         // 0..1 : 64-col slab
  const int l15 = lane & 15;
  const int quad = lane >> 4;
  const int m0 = blockIdx.x * 128;
  const int n0 = blockIdx.y * 128;

  float4e acc[4][4];
#pragma unroll
  for (int i = 0; i < 4; ++i)
#pragma unroll
    for (int j = 0; j < 4; ++j) acc[i][j] = 0.0f;

  // staging index maps
  const int ar = tid >> 1;            // A row 0..127
  const int ac0 = (tid & 1) * 16;     // A col base (2 threads/row)
  const int wn4 = (tid & 31) * 4;     // W col group (4 n)
  const int wk2 = (tid >> 5) * 4;     // W k group (4 k)

  for (int k0 = 0; k0 < K; k0 += 32) {
    // ---- stage A tile (row-major, split hi/lo) ----
    {
      const int gm = m0 + ar;
      const float* arow = A + (long)gm * K + k0 + ac0;
#pragma unroll
      for (int u = 0; u < 4; ++u) {
        float4 v = (gm < M) ? *(const float4*)(arow + u * 4)
                            : make_float4(0.f, 0.f, 0.f, 0.f);
        unsigned short h0 = f2bf(v.x), h1 = f2bf(v.y), h2 = f2bf(v.z), h3 = f2bf(v.w);
        unsigned short q0 = f2bf(v.x - bf2f(h0)), q1 = f2bf(v.y - bf2f(h1));
        unsigned short q2 = f2bf(v.z - bf2f(h2)), q3 = f2bf(v.w - bf2f(h3));
        int c = ac0 + u * 4;
        *(unsigned*)&Ah[ar][c]     = pack2(h0, h1);
        *(unsigned*)&Ah[ar][c + 2] = pack2(h2, h3);
        *(unsigned*)&Al[ar][c]     = pack2(q0, q1);
        *(unsigned*)&Al[ar][c + 2] = pack2(q2, q3);
      }
    }
    // ---- stage W tile transposed: Bh/Bl[n][k] ----
    {
      float4 w[4];
#pragma unroll
      for (int kk = 0; kk < 4; ++kk)
        w[kk] = *(const float4*)(W + (long)(k0 + wk2 + kk) * N + n0 + wn4);
#pragma unroll
      for (int n = 0; n < 4; ++n) {
        float f0 = ((const float*)&w[0])[n];
        float f1 = ((const float*)&w[1])[n];
        float f2 = ((const float*)&w[2])[n];
        float f3 = ((const float*)&w[3])[n];
        unsigned short h0 = f2bf(f0), h1 = f2bf(f1), h2 = f2bf(f2), h3 = f2bf(f3);
        unsigned short q0 = f2bf(f0 - bf2f(h0)), q1 = f2bf(f1 - bf2f(h1));
        unsigned short q2 = f2bf(f2 - bf2f(h2)), q3 = f2bf(f3 - bf2f(h3));
        *(unsigned*)&Bh[wn4 + n][wk2]     = pack2(h0, h1);
        *(unsigned*)&Bh[wn4 + n][wk2 + 2] = pack2(h2, h3);
        *(unsigned*)&Bl[wn4 + n][wk2]     = pack2(q0, q1);
        *(unsigned*)&Bl[wn4 + n][wk2 + 2] = pack2(q2, q3);
      }
    }
    __syncthreads();

    // ---- fragment loads (contiguous b128) ----
    short8 a_h[4], a_l[4], b_h[4], b_l[4];
#pragma unroll
    for (int i = 0; i < 4; ++i) {
      int r = wmi * 64 + i * 16 + l15;
      a_h[i] = *(const short8*)&Ah[r][quad * 8];
      a_l[i] = *(const short8*)&Al[r][quad * 8];
    }
#pragma unroll
    for (int j = 0; j < 4; ++j) {
      int c = wni * 64 + j * 16 + l15;
      b_h[j] = *(const short8*)&Bh[c][quad * 8];
      b_l[j] = *(const short8*)&Bl[c][quad * 8];
    }

    // ---- 3-pass split MFMA ----
#pragma unroll
    for (int i = 0; i < 4; ++i)
#pragma unroll
      for (int j = 0; j < 4; ++j) {
        acc[i][j] = __builtin_amdgcn_mfma_f32_16x16x32_bf16(a_h[i], b_h[j], acc[i][j], 0, 0, 0);
        acc[i][j] = __builtin_amdgcn_mfma_f32_16x16x32_bf16(a_h[i], b_l[j], acc[i][j], 0, 0, 0);
        acc[i][j] = __builtin_amdgcn_mfma_f32_16x16x32_bf16(a_l[i], b_h[j], acc[i][j], 0, 0, 0);
      }
    __syncthreads();
  }

  // ---- epilogue: bias (+relu), C/D layout col=lane&15, row=quad*4+reg ----
#pragma unroll
  for (int j = 0; j < 4; ++j) {
    int col = n0 + wni * 64 + j * 16 + l15;
    float bj = bias[col];
#pragma unroll
    for (int i = 0; i < 4; ++i) {
      int rbase = m0 + wmi * 64 + i * 16 + quad * 4;
#pragma unroll
      for (int r = 0; r < 4; ++r) {
        int row = rbase + r;
        if (row < M) {
          float v = acc[i][j][r] + bj;
          if constexpr (RELU) v = fmaxf(v, 0.0f);
          out[(long)row * N + col] = v;
        }
      }
    }
  }
}

extern "C" void kernel_launch(void* const* d_in, const int* in_sizes, int n_in,
                              void* d_out, int out_size, void* d_ws, size_t ws_size,
                              hipStream_t stream) {
  const float* x    = (const float*)d_in[0];
  const int*   ei   = (const int*)d_in[1];
  const float* eps1 = (const float*)d_in[2];
  const float* W1a  = (const float*)d_in[3];
  const float* b1a  = (const float*)d_in[4];
  const float* W1b  = (const float*)d_in[5];
  const float* b1b  = (const float*)d_in[6];
  const float* eps2 = (const float*)d_in[7];
  const float* W2a  = (const float*)d_in[8];
  const float* b2a  = (const float*)d_in[9];
  const float* W2b  = (const float*)d_in[10];
  const float* b2b  = (const float*)d_in[11];
  float* out = (float*)d_out;

  const int* srcp = ei;
  const int* dstp = ei + N_EDGES;

  // Workspace: two N*256 fp32 buffers (204.8 MB — proven to fit).
  char* ws = (char*)d_ws;
  const size_t SZ = (size_t)N_NODES * 256 * sizeof(float);
  float* B1 = (float*)(ws);
  float* B2 = (float*)(ws + SZ);

  // CSR scratch in d_out (dead before the final GEMM writes d_out).
  char* ob = (char*)d_out;
  int* deg       = (int*)(ob);
  int* rowStart  = (int*)(ob + 400 * 1024);
  int* sortedSrc = (int*)(ob + 800 * 1024);

  dim3 blk(256);
  dim3 gEdges((N_EDGES + 255) / 256);
  dim3 gAgg((N_NODES + 3) / 4);
  const int MT = (N_NODES + 127) / 128;   // 782
  dim3 gG2(MT, 2);                        // N=256
  dim3 gG1(MT, 1);                        // N=128

  // ---- CSR build ----
  hipMemsetAsync(deg, 0, N_NODES * sizeof(int), stream);
  hist_k<<<gEdges, blk, 0, stream>>>(dstp, deg, N_EDGES);
  scan_k<<<1, 1024, 0, stream>>>(deg, rowStart, N_NODES);
  fill_k<<<gEdges, blk, 0, stream>>>(srcp, dstp, rowStart, sortedSrc, N_EDGES);
  // rowStart is now rowEnd.

  // ---- Layer 1 ----
  agg_k<128><<<gAgg, blk, 0, stream>>>(x, x, eps1, rowStart, sortedSrc, B1, N_NODES);
  gemm_bf16s_k<true><<<gG2, blk, 0, stream>>>(B1, W1a, b1a, B2, N_NODES, 128, 256);
  gemm_bf16s_k<true><<<gG2, blk, 0, stream>>>(B2, W1b, b1b, B1, N_NODES, 256, 256);

  // ---- Layer 2 ----
  agg_k<256><<<gAgg, blk, 0, stream>>>(B1, B1, eps2, rowStart, sortedSrc, B2, N_NODES);
  gemm_bf16s_k<true><<<gG2, blk, 0, stream>>>(B2, W2a, b2a, B1, N_NODES, 256, 256);
  gemm_bf16s_k<false><<<gG1, blk, 0, stream>>>(B1, W2b, b2b, out, N_NODES, 256, 128);
}

// Round 5
// 1110.754 us; speedup vs baseline: 2.3980x; 1.0388x over previous
//
#include <hip/hip_runtime.h>

#define N_NODES 100000
#define N_EDGES 1600000

typedef __attribute__((ext_vector_type(8))) short short8;
typedef __attribute__((ext_vector_type(4))) float float4e;

// async 16B global->LDS copy (lane-contiguous LDS dest)
#define GLDS16(g, l)                                                   \
  __builtin_amdgcn_global_load_lds(                                    \
      (const __attribute__((address_space(1))) unsigned int*)(g),      \
      (__attribute__((address_space(3))) unsigned int*)(l), 16, 0, 0)

// ---------------------------------------------------------------------------
// bf16 split helpers (RNE)
// ---------------------------------------------------------------------------
__device__ __forceinline__ unsigned short f2bf(float f) {
  unsigned u = __float_as_uint(f);
  u += 0x7FFFu + ((u >> 16) & 1u);
  return (unsigned short)(u >> 16);
}
__device__ __forceinline__ float bf2f(unsigned short h) {
  return __uint_as_float(((unsigned)h) << 16);
}

// ===========================================================================
// CSR build (rebuilt every call; scratch in d_out, dead before final GEMM).
// ===========================================================================
__global__ __launch_bounds__(256) void hist_k(const int* __restrict__ dst,
                                              int* __restrict__ deg, int nE) {
  int i = blockIdx.x * blockDim.x + threadIdx.x;
  if (i < nE) atomicAdd(&deg[dst[i]], 1);
}

__global__ __launch_bounds__(1024) void scan_k(const int* __restrict__ deg,
                                               int* __restrict__ rowStart, int n) {
  __shared__ int part[1024];
  const int tid = threadIdx.x;
  const int chunk = (n + 1023) >> 10;
  const int base = tid * chunk;
  const int end = min(base + chunk, n);
  int s = 0;
  for (int i = base; i < end; ++i) s += deg[i];
  part[tid] = s;
  __syncthreads();
  for (int off = 1; off < 1024; off <<= 1) {
    int v = (tid >= off) ? part[tid - off] : 0;
    __syncthreads();
    part[tid] += v;
    __syncthreads();
  }
  int run = part[tid] - s;
  for (int i = base; i < end; ++i) {
    rowStart[i] = run;
    run += deg[i];
  }
}

__global__ __launch_bounds__(256) void fill_k(const int* __restrict__ src,
                                              const int* __restrict__ dst,
                                              int* __restrict__ cursor,
                                              int* __restrict__ sortedSrc, int nE) {
  int i = blockIdx.x * blockDim.x + threadIdx.x;
  if (i < nE) {
    int p = atomicAdd(&cursor[dst[i]], 1);
    sortedSrc[p] = src[i];
  }
}

// ===========================================================================
// Weight prep: W[K][N] fp32 -> transposed bf16 hi/lo planes [N][K].
// ===========================================================================
__global__ __launch_bounds__(256) void wprep_k(
    const float* __restrict__ W, unsigned short* __restrict__ th,
    unsigned short* __restrict__ tl, int K, int N) {
  int i = blockIdx.x * blockDim.x + threadIdx.x;
  if (i < K * N) {
    int k = i / N, n = i % N;
    float v = W[i];
    unsigned short h = f2bf(v);
    unsigned short l = f2bf(v - bf2f(h));
    th[(long)n * K + k] = h;
    tl[(long)n * K + k] = l;
  }
}

// ===========================================================================
// CSR gather-sum + GIN combine -> bf16 hi/lo planes:
//   res = (1+eps)*x[n] + sum feat[src];  oh/ol = split(res)
// One wave per node.
// ===========================================================================
template <int C>
__global__ __launch_bounds__(256) void agg_hilo_k(
    const float* __restrict__ feat, const float* __restrict__ xin,
    const float* __restrict__ epsp, const int* __restrict__ rowEnd,
    const int* __restrict__ sortedSrc, unsigned short* __restrict__ oh,
    unsigned short* __restrict__ ol, int M) {
  constexpr int V = C / 64;
  const int lane = threadIdx.x & 63;
  const int w = (int)((blockIdx.x * blockDim.x + threadIdx.x) >> 6);
  if (w >= M) return;
  const int start = w ? rowEnd[w - 1] : 0;
  const int end = rowEnd[w];
  const int c0 = lane * V;

  float acc[V] = {};
  int e = start;
  for (; e + 4 <= end; e += 4) {
    int s0 = sortedSrc[e + 0];
    int s1 = sortedSrc[e + 1];
    int s2 = sortedSrc[e + 2];
    int s3 = sortedSrc[e + 3];
    const float* r0 = feat + (long)s0 * C + c0;
    const float* r1 = feat + (long)s1 * C + c0;
    const float* r2 = feat + (long)s2 * C + c0;
    const float* r3 = feat + (long)s3 * C + c0;
    if constexpr (V == 4) {
      float4 a = *(const float4*)r0, b = *(const float4*)r1;
      float4 c = *(const float4*)r2, d = *(const float4*)r3;
      acc[0] += a.x + b.x + c.x + d.x;
      acc[1] += a.y + b.y + c.y + d.y;
      acc[2] += a.z + b.z + c.z + d.z;
      acc[3] += a.w + b.w + c.w + d.w;
    } else {
      float2 a = *(const float2*)r0, b = *(const float2*)r1;
      float2 c = *(const float2*)r2, d = *(const float2*)r3;
      acc[0] += a.x + b.x + c.x + d.x;
      acc[1] += a.y + b.y + c.y + d.y;
    }
  }
  for (; e < end; ++e) {
    const float* r = feat + (long)sortedSrc[e] * C + c0;
    if constexpr (V == 4) {
      float4 a = *(const float4*)r;
      acc[0] += a.x; acc[1] += a.y; acc[2] += a.z; acc[3] += a.w;
    } else {
      float2 a = *(const float2*)r;
      acc[0] += a.x; acc[1] += a.y;
    }
  }

  const float s = 1.0f + epsp[0];
  const float* xr = xin + (long)w * C + c0;
  unsigned short hv[V], lv[V];
#pragma unroll
  for (int v = 0; v < V; ++v) {
    float res = fmaf(s, xr[v], acc[v]);
    hv[v] = f2bf(res);
    lv[v] = f2bf(res - bf2f(hv[v]));
  }
  if constexpr (V == 4) {
    *(ushort4*)&oh[(long)w * C + c0] = make_ushort4(hv[0], hv[1], hv[2], hv[3]);
    *(ushort4*)&ol[(long)w * C + c0] = make_ushort4(lv[0], lv[1], lv[2], lv[3]);
  } else {
    *(ushort2*)&oh[(long)w * C + c0] = make_ushort2(hv[0], hv[1]);
    *(ushort2*)&ol[(long)w * C + c0] = make_ushort2(lv[0], lv[1]);
  }
}

// ===========================================================================
// Split-bf16 MFMA GEMM, m97 structure.
//   A planes: Ah/Al [M][K] bf16.  B planes: Bth/Btl [N][K] bf16 (transposed).
//   out = act(A@W + bias); HILO: write bf16 hi/lo planes; else fp32.
// 128x128 tile, BK=32, 4 waves, 4x4 frags, 3-pass split MFMA.
// LDS: 4 unpadded [128][32] bf16 tiles staged via global_load_lds width-16.
// ===========================================================================
template <bool RELU, bool HILO>
__global__ __launch_bounds__(256) void gemm_mfma_k(
    const unsigned short* __restrict__ Ah, const unsigned short* __restrict__ Al,
    const unsigned short* __restrict__ Bth, const unsigned short* __restrict__ Btl,
    const float* __restrict__ bias, float* __restrict__ outf,
    unsigned short* __restrict__ oh, unsigned short* __restrict__ ol,
    int M, int K, int N) {
  __shared__ unsigned short Ahs[128 * 32];
  __shared__ unsigned short Als[128 * 32];
  __shared__ unsigned short Bhs[128 * 32];
  __shared__ unsigned short Bls[128 * 32];

  const int tid = threadIdx.x;
  const int lane = tid & 63;
  const int wave = tid >> 6;
  const int wmi = wave >> 1;
  const int wni = wave & 1;
  const int l15 = lane & 15;
  const int quad = lane >> 4;
  const int m0 = blockIdx.x * 128;
  const int n0 = blockIdx.y * 128;

  // staging map: each thread copies 8 shorts (16B); two row-halves per plane
  const int srow = tid >> 2;          // 0..63
  const int scol = (tid & 3) * 8;     // 0,8,16,24

  float4e acc[4][4];
#pragma unroll
  for (int i = 0; i < 4; ++i)
#pragma unroll
    for (int j = 0; j < 4; ++j) acc[i][j] = 0.0f;

  for (int k0 = 0; k0 < K; k0 += 32) {
    // ---- async stage: A planes (guarded M-tail) + B planes ----
    {
      long ga0 = (long)(m0 + srow) * K + k0 + scol;
      long ga1 = (long)(m0 + 64 + srow) * K + k0 + scol;
      if (m0 + srow < M) {
        GLDS16(Ah + ga0, &Ahs[tid * 8]);
        GLDS16(Al + ga0, &Als[tid * 8]);
      }
      if (m0 + 64 + srow < M) {
        GLDS16(Ah + ga1, &Ahs[(256 + tid) * 8]);
        GLDS16(Al + ga1, &Als[(256 + tid) * 8]);
      }
      long gb0 = (long)(n0 + srow) * K + k0 + scol;
      long gb1 = (long)(n0 + 64 + srow) * K + k0 + scol;
      GLDS16(Bth + gb0, &Bhs[tid * 8]);
      GLDS16(Btl + gb0, &Bls[tid * 8]);
      GLDS16(Bth + gb1, &Bhs[(256 + tid) * 8]);
      GLDS16(Btl + gb1, &Bls[(256 + tid) * 8]);
    }
    __syncthreads();  // drains vmcnt before LDS reads

    short8 a_h[4], a_l[4], b_h[4], b_l[4];
#pragma unroll
    for (int i = 0; i < 4; ++i) {
      int r = wmi * 64 + i * 16 + l15;
      a_h[i] = *(const short8*)&Ahs[r * 32 + quad * 8];
      a_l[i] = *(const short8*)&Als[r * 32 + quad * 8];
    }
#pragma unroll
    for (int j = 0; j < 4; ++j) {
      int c = wni * 64 + j * 16 + l15;
      b_h[j] = *(const short8*)&Bhs[c * 32 + quad * 8];
      b_l[j] = *(const short8*)&Bls[c * 32 + quad * 8];
    }

#pragma unroll
    for (int i = 0; i < 4; ++i)
#pragma unroll
      for (int j = 0; j < 4; ++j) {
        acc[i][j] = __builtin_amdgcn_mfma_f32_16x16x32_bf16(a_h[i], b_h[j], acc[i][j], 0, 0, 0);
        acc[i][j] = __builtin_amdgcn_mfma_f32_16x16x32_bf16(a_h[i], b_l[j], acc[i][j], 0, 0, 0);
        acc[i][j] = __builtin_amdgcn_mfma_f32_16x16x32_bf16(a_l[i], b_h[j], acc[i][j], 0, 0, 0);
      }
    __syncthreads();  // LDS reuse next iter
  }

  // ---- epilogue: C/D layout col=lane&15, row=quad*4+reg ----
#pragma unroll
  for (int j = 0; j < 4; ++j) {
    int col = n0 + wni * 64 + j * 16 + l15;
    float bj = bias[col];
#pragma unroll
    for (int i = 0; i < 4; ++i) {
      int rbase = m0 + wmi * 64 + i * 16 + quad * 4;
#pragma unroll
      for (int r = 0; r < 4; ++r) {
        int row = rbase + r;
        if (row < M) {
          float v = acc[i][j][r] + bj;
          if constexpr (RELU) v = fmaxf(v, 0.0f);
          if constexpr (HILO) {
            unsigned short h = f2bf(v);
            oh[(long)row * N + col] = h;
            ol[(long)row * N + col] = f2bf(v - bf2f(h));
          } else {
            outf[(long)row * N + col] = v;
          }
        }
      }
    }
  }
}

extern "C" void kernel_launch(void* const* d_in, const int* in_sizes, int n_in,
                              void* d_out, int out_size, void* d_ws, size_t ws_size,
                              hipStream_t stream) {
  const float* x    = (const float*)d_in[0];
  const int*   ei   = (const int*)d_in[1];
  const float* eps1 = (const float*)d_in[2];
  const float* W1a  = (const float*)d_in[3];
  const float* b1a  = (const float*)d_in[4];
  const float* W1b  = (const float*)d_in[5];
  const float* b1b  = (const float*)d_in[6];
  const float* eps2 = (const float*)d_in[7];
  const float* W2a  = (const float*)d_in[8];
  const float* b2a  = (const float*)d_in[9];
  const float* W2b  = (const float*)d_in[10];
  const float* b2b  = (const float*)d_in[11];
  float* out = (float*)d_out;

  const int* srcp = ei;
  const int* dstp = ei + N_EDGES;

  // ---- workspace: two 102.4MB halves, cycled ----
  char* ws = (char*)d_ws;
  const size_t SZ = (size_t)N_NODES * 256 * sizeof(float);  // 102.4 MB
  char* P1 = ws;
  char* P2 = ws + SZ;

  unsigned short* C1h = (unsigned short*)P1;                  // [M][128]
  unsigned short* C1l = C1h + (size_t)N_NODES * 128;
  unsigned short* T1h = (unsigned short*)P2;                  // [M][256]
  unsigned short* T1l = T1h + (size_t)N_NODES * 256;
  float*          hbuf = (float*)P1;                          // [M][256] fp32
  unsigned short* C2h = (unsigned short*)P2;                  // [M][256]
  unsigned short* C2l = C2h + (size_t)N_NODES * 256;
  unsigned short* T2h = (unsigned short*)P1;                  // [M][256]
  unsigned short* T2l = T2h + (size_t)N_NODES * 256;
  unsigned short* W2bh = (unsigned short*)P2;                 // [128][256] (late prep)
  unsigned short* W2bl = W2bh + 128 * 256;

  // ---- d_out scratch: CSR + early weight planes (all dead before final GEMM) ----
  char* ob = (char*)d_out;
  int* deg       = (int*)(ob);
  int* rowStart  = (int*)(ob + 400 * 1024);
  int* sortedSrc = (int*)(ob + 800 * 1024);              // ends at ~7.2 MB
  size_t wofs = 7340032;                                 // 7 MiB mark
  unsigned short* W1ah = (unsigned short*)(ob + wofs);   // [256][128] 64KB
  unsigned short* W1al = W1ah + 256 * 128;
  unsigned short* W1bh = (unsigned short*)(ob + wofs + 2 * 65536);  // [256][256] 128KB
  unsigned short* W1bl = W1bh + 256 * 256;
  unsigned short* W2ah = (unsigned short*)(ob + wofs + 2 * 65536 + 2 * 131072);
  unsigned short* W2al = W2ah + 256 * 256;

  dim3 blk(256);
  dim3 gEdges((N_EDGES + 255) / 256);
  dim3 gAgg((N_NODES + 3) / 4);
  const int MT = (N_NODES + 127) / 128;   // 782
  dim3 gG2(MT, 2);                        // N=256
  dim3 gG1(MT, 1);                        // N=128
  dim3 gW1((128 * 256 + 255) / 256);
  dim3 gW2((256 * 256 + 255) / 256);

  // ---- CSR build + weight prep ----
  hipMemsetAsync(deg, 0, N_NODES * sizeof(int), stream);
  hist_k<<<gEdges, blk, 0, stream>>>(dstp, deg, N_EDGES);
  scan_k<<<1, 1024, 0, stream>>>(deg, rowStart, N_NODES);
  fill_k<<<gEdges, blk, 0, stream>>>(srcp, dstp, rowStart, sortedSrc, N_EDGES);
  wprep_k<<<gW1, blk, 0, stream>>>(W1a, W1ah, W1al, 128, 256);
  wprep_k<<<gW2, blk, 0, stream>>>(W1b, W1bh, W1bl, 256, 256);
  wprep_k<<<gW2, blk, 0, stream>>>(W2a, W2ah, W2al, 256, 256);

  // ---- Layer 1 ----
  agg_hilo_k<128><<<gAgg, blk, 0, stream>>>(x, x, eps1, rowStart, sortedSrc,
                                            C1h, C1l, N_NODES);
  gemm_mfma_k<true, true><<<gG2, blk, 0, stream>>>(
      C1h, C1l, W1ah, W1al, b1a, nullptr, T1h, T1l, N_NODES, 128, 256);
  gemm_mfma_k<true, false><<<gG2, blk, 0, stream>>>(
      T1h, T1l, W1bh, W1bl, b1b, hbuf, nullptr, nullptr, N_NODES, 256, 256);

  // ---- Layer 2 ----
  agg_hilo_k<256><<<gAgg, blk, 0, stream>>>(hbuf, hbuf, eps2, rowStart, sortedSrc,
                                            C2h, C2l, N_NODES);
  gemm_mfma_k<true, true><<<gG2, blk, 0, stream>>>(
      C2h, C2l, W2ah, W2al, b2a, nullptr, T2h, T2l, N_NODES, 256, 256);
  wprep_k<<<gW1, blk, 0, stream>>>(W2b, W2bh, W2bl, 256, 128);  // C2 dead now
  gemm_mfma_k<false, false><<<gG1, blk, 0, stream>>>(
      T2h, T2l, W2bh, W2bl, b2b, out, nullptr, nullptr, N_NODES, 256, 128);
}

// Round 6
// 1055.642 us; speedup vs baseline: 2.5232x; 1.0522x over previous
//
#include <hip/hip_runtime.h>

#define N_NODES 100000
#define N_EDGES 1600000

typedef __attribute__((ext_vector_type(8))) short short8;
typedef __attribute__((ext_vector_type(4))) float float4e;

// async 16B global->LDS copy (lane-contiguous LDS dest)
#define GLDS16(g, l)                                                   \
  __builtin_amdgcn_global_load_lds(                                    \
      (const __attribute__((address_space(1))) unsigned int*)(g),      \
      (__attribute__((address_space(3))) unsigned int*)(l), 16, 0, 0)

// ---------------------------------------------------------------------------
// bf16 split helpers (RNE)
// ---------------------------------------------------------------------------
__device__ __forceinline__ unsigned short f2bf(float f) {
  unsigned u = __float_as_uint(f);
  u += 0x7FFFu + ((u >> 16) & 1u);
  return (unsigned short)(u >> 16);
}
__device__ __forceinline__ float bf2f(unsigned short h) {
  return __uint_as_float(((unsigned)h) << 16);
}

// ===========================================================================
// CSR build (rebuilt every call; scratch in d_out, dead before final GEMM).
// ===========================================================================
__global__ __launch_bounds__(256) void hist_k(const int* __restrict__ dst,
                                              int* __restrict__ deg, int nE) {
  int i = blockIdx.x * blockDim.x + threadIdx.x;
  if (i < nE) atomicAdd(&deg[dst[i]], 1);
}

__global__ __launch_bounds__(1024) void scan_k(const int* __restrict__ deg,
                                               int* __restrict__ rowStart, int n) {
  __shared__ int part[1024];
  const int tid = threadIdx.x;
  const int chunk = (n + 1023) >> 10;
  const int base = tid * chunk;
  const int end = min(base + chunk, n);
  int s = 0;
  for (int i = base; i < end; ++i) s += deg[i];
  part[tid] = s;
  __syncthreads();
  for (int off = 1; off < 1024; off <<= 1) {
    int v = (tid >= off) ? part[tid - off] : 0;
    __syncthreads();
    part[tid] += v;
    __syncthreads();
  }
  int run = part[tid] - s;
  for (int i = base; i < end; ++i) {
    rowStart[i] = run;
    run += deg[i];
  }
}

__global__ __launch_bounds__(256) void fill_k(const int* __restrict__ src,
                                              const int* __restrict__ dst,
                                              int* __restrict__ cursor,
                                              int* __restrict__ sortedSrc, int nE) {
  int i = blockIdx.x * blockDim.x + threadIdx.x;
  if (i < nE) {
    int p = atomicAdd(&cursor[dst[i]], 1);
    sortedSrc[p] = src[i];
  }
}

// ===========================================================================
// Weight prep: W[K][N] fp32 -> transposed bf16 hi/lo planes [N][K].
// ===========================================================================
__global__ __launch_bounds__(256) void wprep_k(
    const float* __restrict__ W, unsigned short* __restrict__ th,
    unsigned short* __restrict__ tl, int K, int N) {
  int i = blockIdx.x * blockDim.x + threadIdx.x;
  if (i < K * N) {
    int k = i / N, n = i % N;
    float v = W[i];
    unsigned short h = f2bf(v);
    unsigned short l = f2bf(v - bf2f(h));
    th[(long)n * K + k] = h;
    tl[(long)n * K + k] = l;
  }
}

// ===========================================================================
// CSR gather-sum + GIN combine -> bf16 hi/lo planes.
// ===========================================================================
template <int C>
__global__ __launch_bounds__(256) void agg_hilo_k(
    const float* __restrict__ feat, const float* __restrict__ xin,
    const float* __restrict__ epsp, const int* __restrict__ rowEnd,
    const int* __restrict__ sortedSrc, unsigned short* __restrict__ oh,
    unsigned short* __restrict__ ol, int M) {
  constexpr int V = C / 64;
  const int lane = threadIdx.x & 63;
  const int w = (int)((blockIdx.x * blockDim.x + threadIdx.x) >> 6);
  if (w >= M) return;
  const int start = w ? rowEnd[w - 1] : 0;
  const int end = rowEnd[w];
  const int c0 = lane * V;

  float acc[V] = {};
  int e = start;
  for (; e + 4 <= end; e += 4) {
    int s0 = sortedSrc[e + 0];
    int s1 = sortedSrc[e + 1];
    int s2 = sortedSrc[e + 2];
    int s3 = sortedSrc[e + 3];
    const float* r0 = feat + (long)s0 * C + c0;
    const float* r1 = feat + (long)s1 * C + c0;
    const float* r2 = feat + (long)s2 * C + c0;
    const float* r3 = feat + (long)s3 * C + c0;
    if constexpr (V == 4) {
      float4 a = *(const float4*)r0, b = *(const float4*)r1;
      float4 c = *(const float4*)r2, d = *(const float4*)r3;
      acc[0] += a.x + b.x + c.x + d.x;
      acc[1] += a.y + b.y + c.y + d.y;
      acc[2] += a.z + b.z + c.z + d.z;
      acc[3] += a.w + b.w + c.w + d.w;
    } else {
      float2 a = *(const float2*)r0, b = *(const float2*)r1;
      float2 c = *(const float2*)r2, d = *(const float2*)r3;
      acc[0] += a.x + b.x + c.x + d.x;
      acc[1] += a.y + b.y + c.y + d.y;
    }
  }
  for (; e < end; ++e) {
    const float* r = feat + (long)sortedSrc[e] * C + c0;
    if constexpr (V == 4) {
      float4 a = *(const float4*)r;
      acc[0] += a.x; acc[1] += a.y; acc[2] += a.z; acc[3] += a.w;
    } else {
      float2 a = *(const float2*)r;
      acc[0] += a.x; acc[1] += a.y;
    }
  }

  const float s = 1.0f + epsp[0];
  const float* xr = xin + (long)w * C + c0;
  unsigned short hv[V], lv[V];
#pragma unroll
  for (int v = 0; v < V; ++v) {
    float res = fmaf(s, xr[v], acc[v]);
    hv[v] = f2bf(res);
    lv[v] = f2bf(res - bf2f(hv[v]));
  }
  if constexpr (V == 4) {
    *(ushort4*)&oh[(long)w * C + c0] = make_ushort4(hv[0], hv[1], hv[2], hv[3]);
    *(ushort4*)&ol[(long)w * C + c0] = make_ushort4(lv[0], lv[1], lv[2], lv[3]);
  } else {
    *(ushort2*)&oh[(long)w * C + c0] = make_ushort2(hv[0], hv[1]);
    *(ushort2*)&ol[(long)w * C + c0] = make_ushort2(lv[0], lv[1]);
  }
}

// ===========================================================================
// Split-bf16 MFMA GEMM, full-N blocks: A staged ONCE from global.
//   Block = 64 rows x N (N = NFRAG*16). 4 waves; wave = 16-row m-frag x NFRAG.
//   A planes [M][K] hi/lo; B planes [N][K] hi/lo (transposed weights).
//   Per K-iter (BK=32): stage A 64x32 hilo (8KB, HBM) + B Nx32 hilo (L2)
//   via global_load_lds w16; 3-pass split MFMA (hh, hl, lh).
// LDS: N=256 -> 40KB; N=128 -> 24KB.
// ===========================================================================
template <int NFRAG, bool RELU, bool HILO>
__global__ __launch_bounds__(256, 3) void gemm_wide_k(
    const unsigned short* __restrict__ Ah, const unsigned short* __restrict__ Al,
    const unsigned short* __restrict__ Bth, const unsigned short* __restrict__ Btl,
    const float* __restrict__ bias, float* __restrict__ outf,
    unsigned short* __restrict__ oh, unsigned short* __restrict__ ol,
    int M, int K) {
  constexpr int N = NFRAG * 16;
  __shared__ unsigned short Ahs[64 * 32];
  __shared__ unsigned short Als[64 * 32];
  __shared__ unsigned short Bhs[N * 32];
  __shared__ unsigned short Bls[N * 32];

  const int tid = threadIdx.x;
  const int lane = tid & 63;
  const int wave = tid >> 6;
  const int l15 = lane & 15;
  const int quad = lane >> 4;
  const int m0 = blockIdx.x * 64;

  float4e acc[NFRAG];
#pragma unroll
  for (int j = 0; j < NFRAG; ++j) acc[j] = 0.0f;

  // staging maps: 16B chunks. A plane: 256 chunks (1/thread); row=c>>2, col=(c&3)*8
  const int a_row = tid >> 2;
  const int a_col = (tid & 3) * 8;
  const bool a_ok = (m0 + a_row) < M;

  for (int k0 = 0; k0 < K; k0 += 32) {
    // ---- A hilo (8KB total) ----
    {
      long ga = (long)(m0 + a_row) * K + k0 + a_col;
      if (a_ok) {
        GLDS16(Ah + ga, &Ahs[tid * 8]);
        GLDS16(Al + ga, &Als[tid * 8]);
      }
    }
    // ---- B hilo (N*32 shorts per plane; NFRAG/4 chunks per thread) ----
#pragma unroll
    for (int u = 0; u < NFRAG / 4; ++u) {
      int c = u * 256 + tid;
      long gb = (long)(c >> 2) * K + k0 + (c & 3) * 8;
      GLDS16(Bth + gb, &Bhs[c * 8]);
      GLDS16(Btl + gb, &Bls[c * 8]);
    }
    __syncthreads();  // drains vmcnt (global_load_lds) before LDS reads

    short8 a_h = *(const short8*)&Ahs[(wave * 16 + l15) * 32 + quad * 8];
    short8 a_l = *(const short8*)&Als[(wave * 16 + l15) * 32 + quad * 8];

#pragma unroll
    for (int j = 0; j < NFRAG; ++j) {
      short8 b_h = *(const short8*)&Bhs[(j * 16 + l15) * 32 + quad * 8];
      short8 b_l = *(const short8*)&Bls[(j * 16 + l15) * 32 + quad * 8];
      acc[j] = __builtin_amdgcn_mfma_f32_16x16x32_bf16(a_h, b_h, acc[j], 0, 0, 0);
      acc[j] = __builtin_amdgcn_mfma_f32_16x16x32_bf16(a_h, b_l, acc[j], 0, 0, 0);
      acc[j] = __builtin_amdgcn_mfma_f32_16x16x32_bf16(a_l, b_h, acc[j], 0, 0, 0);
    }
    __syncthreads();  // LDS reuse next iter
  }

  // ---- epilogue: C/D layout col=lane&15, row=quad*4+reg ----
#pragma unroll
  for (int j = 0; j < NFRAG; ++j) {
    int col = j * 16 + l15;
    float bj = bias[col];
    int rbase = m0 + wave * 16 + quad * 4;
#pragma unroll
    for (int r = 0; r < 4; ++r) {
      int row = rbase + r;
      if (row < M) {
        float v = acc[j][r] + bj;
        if constexpr (RELU) v = fmaxf(v, 0.0f);
        if constexpr (HILO) {
          unsigned short h = f2bf(v);
          oh[(long)row * N + col] = h;
          ol[(long)row * N + col] = f2bf(v - bf2f(h));
        } else {
          outf[(long)row * N + col] = v;
        }
      }
    }
  }
}

extern "C" void kernel_launch(void* const* d_in, const int* in_sizes, int n_in,
                              void* d_out, int out_size, void* d_ws, size_t ws_size,
                              hipStream_t stream) {
  const float* x    = (const float*)d_in[0];
  const int*   ei   = (const int*)d_in[1];
  const float* eps1 = (const float*)d_in[2];
  const float* W1a  = (const float*)d_in[3];
  const float* b1a  = (const float*)d_in[4];
  const float* W1b  = (const float*)d_in[5];
  const float* b1b  = (const float*)d_in[6];
  const float* eps2 = (const float*)d_in[7];
  const float* W2a  = (const float*)d_in[8];
  const float* b2a  = (const float*)d_in[9];
  const float* W2b  = (const float*)d_in[10];
  const float* b2b  = (const float*)d_in[11];
  float* out = (float*)d_out;

  const int* srcp = ei;
  const int* dstp = ei + N_EDGES;

  // ---- workspace: two 102.4MB halves, cycled ----
  char* ws = (char*)d_ws;
  const size_t SZ = (size_t)N_NODES * 256 * sizeof(float);  // 102.4 MB
  char* P1 = ws;
  char* P2 = ws + SZ;

  unsigned short* C1h = (unsigned short*)P1;                  // [M][128]
  unsigned short* C1l = C1h + (size_t)N_NODES * 128;
  unsigned short* T1h = (unsigned short*)P2;                  // [M][256]
  unsigned short* T1l = T1h + (size_t)N_NODES * 256;
  float*          hbuf = (float*)P1;                          // [M][256] fp32
  unsigned short* C2h = (unsigned short*)P2;                  // [M][256]
  unsigned short* C2l = C2h + (size_t)N_NODES * 256;
  unsigned short* T2h = (unsigned short*)P1;                  // [M][256]
  unsigned short* T2l = T2h + (size_t)N_NODES * 256;
  unsigned short* W2bh = (unsigned short*)P2;                 // [128][256] (late prep)
  unsigned short* W2bl = W2bh + 128 * 256;

  // ---- d_out scratch: CSR + early weight planes (dead before final GEMM) ----
  char* ob = (char*)d_out;
  int* deg       = (int*)(ob);
  int* rowStart  = (int*)(ob + 400 * 1024);
  int* sortedSrc = (int*)(ob + 800 * 1024);              // ends at ~7.2 MB
  size_t wofs = 7340032;                                 // 7 MiB mark
  unsigned short* W1ah = (unsigned short*)(ob + wofs);   // [256][128]
  unsigned short* W1al = W1ah + 256 * 128;
  unsigned short* W1bh = (unsigned short*)(ob + wofs + 2 * 65536);  // [256][256]
  unsigned short* W1bl = W1bh + 256 * 256;
  unsigned short* W2ah = (unsigned short*)(ob + wofs + 2 * 65536 + 2 * 131072);
  unsigned short* W2al = W2ah + 256 * 256;

  dim3 blk(256);
  dim3 gEdges((N_EDGES + 255) / 256);
  dim3 gAgg((N_NODES + 3) / 4);
  dim3 gGemm((N_NODES + 63) / 64);        // 1563 blocks, full-N
  dim3 gW1((128 * 256 + 255) / 256);
  dim3 gW2((256 * 256 + 255) / 256);

  // ---- CSR build + weight prep ----
  hipMemsetAsync(deg, 0, N_NODES * sizeof(int), stream);
  hist_k<<<gEdges, blk, 0, stream>>>(dstp, deg, N_EDGES);
  scan_k<<<1, 1024, 0, stream>>>(deg, rowStart, N_NODES);
  fill_k<<<gEdges, blk, 0, stream>>>(srcp, dstp, rowStart, sortedSrc, N_EDGES);
  wprep_k<<<gW1, blk, 0, stream>>>(W1a, W1ah, W1al, 128, 256);
  wprep_k<<<gW2, blk, 0, stream>>>(W1b, W1bh, W1bl, 256, 256);
  wprep_k<<<gW2, blk, 0, stream>>>(W2a, W2ah, W2al, 256, 256);

  // ---- Layer 1 ----
  agg_hilo_k<128><<<gAgg, blk, 0, stream>>>(x, x, eps1, rowStart, sortedSrc,
                                            C1h, C1l, N_NODES);
  gemm_wide_k<16, true, true><<<gGemm, blk, 0, stream>>>(
      C1h, C1l, W1ah, W1al, b1a, nullptr, T1h, T1l, N_NODES, 128);
  gemm_wide_k<16, true, false><<<gGemm, blk, 0, stream>>>(
      T1h, T1l, W1bh, W1bl, b1b, hbuf, nullptr, nullptr, N_NODES, 256);

  // ---- Layer 2 ----
  agg_hilo_k<256><<<gAgg, blk, 0, stream>>>(hbuf, hbuf, eps2, rowStart, sortedSrc,
                                            C2h, C2l, N_NODES);
  gemm_wide_k<16, true, true><<<gGemm, blk, 0, stream>>>(
      C2h, C2l, W2ah, W2al, b2a, nullptr, T2h, T2l, N_NODES, 256);
  wprep_k<<<gW1, blk, 0, stream>>>(W2b, W2bh, W2bl, 256, 128);  // C2 dead now
  gemm_wide_k<8, false, false><<<gGemm, blk, 0, stream>>>(
      T2h, T2l, W2bh, W2bl, b2b, out, nullptr, nullptr, N_NODES, 256);
}

// Round 7
// 950.437 us; speedup vs baseline: 2.8025x; 1.1107x over previous
//
#include <hip/hip_runtime.h>

#define N_NODES 100000
#define N_EDGES 1600000

typedef __attribute__((ext_vector_type(8))) short short8;
typedef __attribute__((ext_vector_type(4))) float float4e;

// async 16B global->LDS copy (lane-contiguous LDS dest)
#define GLDS16(g, l)                                                   \
  __builtin_amdgcn_global_load_lds(                                    \
      (const __attribute__((address_space(1))) unsigned int*)(g),      \
      (__attribute__((address_space(3))) unsigned int*)(l), 16, 0, 0)

// ---------------------------------------------------------------------------
// bf16 split helpers (RNE)
// ---------------------------------------------------------------------------
__device__ __forceinline__ unsigned short f2bf(float f) {
  unsigned u = __float_as_uint(f);
  u += 0x7FFFu + ((u >> 16) & 1u);
  return (unsigned short)(u >> 16);
}
__device__ __forceinline__ float bf2f(unsigned short h) {
  return __uint_as_float(((unsigned)h) << 16);
}

// ===========================================================================
// CSR build (rebuilt every call; scratch in d_out, dead before final GEMM).
// ===========================================================================
__global__ __launch_bounds__(256) void hist_k(const int* __restrict__ dst,
                                              int* __restrict__ deg, int nE) {
  int i = blockIdx.x * blockDim.x + threadIdx.x;
  if (i < nE) atomicAdd(&deg[dst[i]], 1);
}

__global__ __launch_bounds__(1024) void scan_k(const int* __restrict__ deg,
                                               int* __restrict__ rowStart, int n) {
  __shared__ int part[1024];
  const int tid = threadIdx.x;
  const int chunk = (n + 1023) >> 10;
  const int base = tid * chunk;
  const int end = min(base + chunk, n);
  int s = 0;
  for (int i = base; i < end; ++i) s += deg[i];
  part[tid] = s;
  __syncthreads();
  for (int off = 1; off < 1024; off <<= 1) {
    int v = (tid >= off) ? part[tid - off] : 0;
    __syncthreads();
    part[tid] += v;
    __syncthreads();
  }
  int run = part[tid] - s;
  for (int i = base; i < end; ++i) {
    rowStart[i] = run;
    run += deg[i];
  }
}

__global__ __launch_bounds__(256) void fill_k(const int* __restrict__ src,
                                              const int* __restrict__ dst,
                                              int* __restrict__ cursor,
                                              int* __restrict__ sortedSrc, int nE) {
  int i = blockIdx.x * blockDim.x + threadIdx.x;
  if (i < nE) {
    int p = atomicAdd(&cursor[dst[i]], 1);
    sortedSrc[p] = src[i];
  }
}

// ===========================================================================
// Weight prep: W[K][N] fp32 -> transposed bf16 hi/lo planes [N][K].
// ===========================================================================
__global__ __launch_bounds__(256) void wprep_k(
    const float* __restrict__ W, unsigned short* __restrict__ th,
    unsigned short* __restrict__ tl, int K, int N) {
  int i = blockIdx.x * blockDim.x + threadIdx.x;
  if (i < K * N) {
    int k = i / N, n = i % N;
    float v = W[i];
    unsigned short h = f2bf(v);
    unsigned short l = f2bf(v - bf2f(h));
    th[(long)n * K + k] = h;
    tl[(long)n * K + k] = l;
  }
}

// x fp32 -> bf16 hi plane (for the gather path)
__global__ __launch_bounds__(256) void xprep_k(const float* __restrict__ x,
                                               unsigned short* __restrict__ xh,
                                               int n) {
  int i = blockIdx.x * blockDim.x + threadIdx.x;
  if (i < n) xh[i] = f2bf(x[i]);
}

// ===========================================================================
// CSR gather-sum (bf16 rows) + GIN combine -> bf16 hi/lo planes.
//   res = (1+eps)*self[n] + sum_{in-edges} bf2f(feat_h[src])
//   XF32: self from fp32 xf; else self = bf2f(xh)+bf2f(xl) (hi/lo planes).
// One wave per node; lane holds C/64 channels (ushort2/ushort4 gathers).
// ===========================================================================
template <int C, bool XF32>
__global__ __launch_bounds__(256) void agg_g16_k(
    const unsigned short* __restrict__ feat_h, const float* __restrict__ xf,
    const unsigned short* __restrict__ xh, const unsigned short* __restrict__ xl,
    const float* __restrict__ epsp, const int* __restrict__ rowEnd,
    const int* __restrict__ sortedSrc, unsigned short* __restrict__ oh,
    unsigned short* __restrict__ ol, int M) {
  constexpr int V = C / 64;
  const int lane = threadIdx.x & 63;
  const int w = (int)((blockIdx.x * blockDim.x + threadIdx.x) >> 6);
  if (w >= M) return;
  const int start = w ? rowEnd[w - 1] : 0;
  const int end = rowEnd[w];
  const int c0 = lane * V;

  float acc[V] = {};
  int e = start;
  for (; e + 4 <= end; e += 4) {
    int s0 = sortedSrc[e + 0];
    int s1 = sortedSrc[e + 1];
    int s2 = sortedSrc[e + 2];
    int s3 = sortedSrc[e + 3];
    if constexpr (V == 4) {
      ushort4 a = *(const ushort4*)(feat_h + (long)s0 * C + c0);
      ushort4 b = *(const ushort4*)(feat_h + (long)s1 * C + c0);
      ushort4 c = *(const ushort4*)(feat_h + (long)s2 * C + c0);
      ushort4 d = *(const ushort4*)(feat_h + (long)s3 * C + c0);
      acc[0] += bf2f(a.x) + bf2f(b.x) + bf2f(c.x) + bf2f(d.x);
      acc[1] += bf2f(a.y) + bf2f(b.y) + bf2f(c.y) + bf2f(d.y);
      acc[2] += bf2f(a.z) + bf2f(b.z) + bf2f(c.z) + bf2f(d.z);
      acc[3] += bf2f(a.w) + bf2f(b.w) + bf2f(c.w) + bf2f(d.w);
    } else {
      ushort2 a = *(const ushort2*)(feat_h + (long)s0 * C + c0);
      ushort2 b = *(const ushort2*)(feat_h + (long)s1 * C + c0);
      ushort2 c = *(const ushort2*)(feat_h + (long)s2 * C + c0);
      ushort2 d = *(const ushort2*)(feat_h + (long)s3 * C + c0);
      acc[0] += bf2f(a.x) + bf2f(b.x) + bf2f(c.x) + bf2f(d.x);
      acc[1] += bf2f(a.y) + bf2f(b.y) + bf2f(c.y) + bf2f(d.y);
    }
  }
  for (; e < end; ++e) {
    const unsigned short* r = feat_h + (long)sortedSrc[e] * C + c0;
    if constexpr (V == 4) {
      ushort4 a = *(const ushort4*)r;
      acc[0] += bf2f(a.x); acc[1] += bf2f(a.y);
      acc[2] += bf2f(a.z); acc[3] += bf2f(a.w);
    } else {
      ushort2 a = *(const ushort2*)r;
      acc[0] += bf2f(a.x); acc[1] += bf2f(a.y);
    }
  }

  const float s = 1.0f + epsp[0];
  float xv[V];
  if constexpr (XF32) {
#pragma unroll
    for (int v = 0; v < V; ++v) xv[v] = xf[(long)w * C + c0 + v];
  } else {
#pragma unroll
    for (int v = 0; v < V; ++v)
      xv[v] = bf2f(xh[(long)w * C + c0 + v]) + bf2f(xl[(long)w * C + c0 + v]);
  }

  unsigned short hv[V], lv[V];
#pragma unroll
  for (int v = 0; v < V; ++v) {
    float res = fmaf(s, xv[v], acc[v]);
    hv[v] = f2bf(res);
    lv[v] = f2bf(res - bf2f(hv[v]));
  }
  if constexpr (V == 4) {
    *(ushort4*)&oh[(long)w * C + c0] = make_ushort4(hv[0], hv[1], hv[2], hv[3]);
    *(ushort4*)&ol[(long)w * C + c0] = make_ushort4(lv[0], lv[1], lv[2], lv[3]);
  } else {
    *(ushort2*)&oh[(long)w * C + c0] = make_ushort2(hv[0], hv[1]);
    *(ushort2*)&ol[(long)w * C + c0] = make_ushort2(lv[0], lv[1]);
  }
}

// ===========================================================================
// Split-bf16 MFMA GEMM, full-N blocks: A staged ONCE from global.
//   Block = 64 rows x N (N = NFRAG*16). 4 waves; wave = 16-row m-frag x NFRAG.
//   Per K-iter (BK=32): stage A 64x32 hilo (HBM) + B Nx32 hilo (L2) via
//   global_load_lds w16; 3-pass split MFMA (hh, hl, lh).
// ===========================================================================
template <int NFRAG, bool RELU, bool HILO>
__global__ __launch_bounds__(256, 3) void gemm_wide_k(
    const unsigned short* __restrict__ Ah, const unsigned short* __restrict__ Al,
    const unsigned short* __restrict__ Bth, const unsigned short* __restrict__ Btl,
    const float* __restrict__ bias, float* __restrict__ outf,
    unsigned short* __restrict__ oh, unsigned short* __restrict__ ol,
    int M, int K) {
  constexpr int N = NFRAG * 16;
  __shared__ unsigned short Ahs[64 * 32];
  __shared__ unsigned short Als[64 * 32];
  __shared__ unsigned short Bhs[N * 32];
  __shared__ unsigned short Bls[N * 32];

  const int tid = threadIdx.x;
  const int lane = tid & 63;
  const int wave = tid >> 6;
  const int l15 = lane & 15;
  const int quad = lane >> 4;
  const int m0 = blockIdx.x * 64;

  float4e acc[NFRAG];
#pragma unroll
  for (int j = 0; j < NFRAG; ++j) acc[j] = 0.0f;

  const int a_row = tid >> 2;
  const int a_col = (tid & 3) * 8;
  const bool a_ok = (m0 + a_row) < M;

  for (int k0 = 0; k0 < K; k0 += 32) {
    {
      long ga = (long)(m0 + a_row) * K + k0 + a_col;
      if (a_ok) {
        GLDS16(Ah + ga, &Ahs[tid * 8]);
        GLDS16(Al + ga, &Als[tid * 8]);
      }
    }
#pragma unroll
    for (int u = 0; u < NFRAG / 4; ++u) {
      int c = u * 256 + tid;
      long gb = (long)(c >> 2) * K + k0 + (c & 3) * 8;
      GLDS16(Bth + gb, &Bhs[c * 8]);
      GLDS16(Btl + gb, &Bls[c * 8]);
    }
    __syncthreads();

    short8 a_h = *(const short8*)&Ahs[(wave * 16 + l15) * 32 + quad * 8];
    short8 a_l = *(const short8*)&Als[(wave * 16 + l15) * 32 + quad * 8];

#pragma unroll
    for (int j = 0; j < NFRAG; ++j) {
      short8 b_h = *(const short8*)&Bhs[(j * 16 + l15) * 32 + quad * 8];
      short8 b_l = *(const short8*)&Bls[(j * 16 + l15) * 32 + quad * 8];
      acc[j] = __builtin_amdgcn_mfma_f32_16x16x32_bf16(a_h, b_h, acc[j], 0, 0, 0);
      acc[j] = __builtin_amdgcn_mfma_f32_16x16x32_bf16(a_h, b_l, acc[j], 0, 0, 0);
      acc[j] = __builtin_amdgcn_mfma_f32_16x16x32_bf16(a_l, b_h, acc[j], 0, 0, 0);
    }
    __syncthreads();
  }

#pragma unroll
  for (int j = 0; j < NFRAG; ++j) {
    int col = j * 16 + l15;
    float bj = bias[col];
    int rbase = m0 + wave * 16 + quad * 4;
#pragma unroll
    for (int r = 0; r < 4; ++r) {
      int row = rbase + r;
      if (row < M) {
        float v = acc[j][r] + bj;
        if constexpr (RELU) v = fmaxf(v, 0.0f);
        if constexpr (HILO) {
          unsigned short h = f2bf(v);
          oh[(long)row * N + col] = h;
          ol[(long)row * N + col] = f2bf(v - bf2f(h));
        } else {
          outf[(long)row * N + col] = v;
        }
      }
    }
  }
}

extern "C" void kernel_launch(void* const* d_in, const int* in_sizes, int n_in,
                              void* d_out, int out_size, void* d_ws, size_t ws_size,
                              hipStream_t stream) {
  const float* x    = (const float*)d_in[0];
  const int*   ei   = (const int*)d_in[1];
  const float* eps1 = (const float*)d_in[2];
  const float* W1a  = (const float*)d_in[3];
  const float* b1a  = (const float*)d_in[4];
  const float* W1b  = (const float*)d_in[5];
  const float* b1b  = (const float*)d_in[6];
  const float* eps2 = (const float*)d_in[7];
  const float* W2a  = (const float*)d_in[8];
  const float* b2a  = (const float*)d_in[9];
  const float* W2b  = (const float*)d_in[10];
  const float* b2b  = (const float*)d_in[11];
  float* out = (float*)d_out;

  const int* srcp = ei;
  const int* dstp = ei + N_EDGES;

  // ---- workspace: two 102.4MB halves, cycled ----
  char* ws = (char*)d_ws;
  const size_t SZ = (size_t)N_NODES * 256 * sizeof(float);  // 102.4 MB
  char* P1 = ws;
  char* P2 = ws + SZ;

  // P1 phase A: C1 hilo [M][128] (51.2MB) + xh [M][128] bf16 (25.6MB)
  unsigned short* C1h = (unsigned short*)P1;
  unsigned short* C1l = C1h + (size_t)N_NODES * 128;
  unsigned short* xh  = C1l + (size_t)N_NODES * 128;
  // P2 phase A: T1 hilo [M][256] (102.4MB)
  unsigned short* T1h = (unsigned short*)P2;
  unsigned short* T1l = T1h + (size_t)N_NODES * 256;
  // P1 phase B: H hilo [M][256] (102.4MB)  (C1/xh dead)
  unsigned short* Hh = (unsigned short*)P1;
  unsigned short* Hl = Hh + (size_t)N_NODES * 256;
  // P2 phase B: C2 hilo [M][256]  (T1 dead)
  unsigned short* C2h = (unsigned short*)P2;
  unsigned short* C2l = C2h + (size_t)N_NODES * 256;
  // P1 phase C: T2 hilo [M][256]  (H dead)
  unsigned short* T2h = (unsigned short*)P1;
  unsigned short* T2l = T2h + (size_t)N_NODES * 256;
  // P2 phase C: W2b planes (C2 dead)
  unsigned short* W2bh = (unsigned short*)P2;
  unsigned short* W2bl = W2bh + 128 * 256;

  // ---- d_out scratch: CSR + early weight planes (dead before final GEMM) ----
  char* ob = (char*)d_out;
  int* deg       = (int*)(ob);
  int* rowStart  = (int*)(ob + 400 * 1024);
  int* sortedSrc = (int*)(ob + 800 * 1024);
  size_t wofs = 7340032;
  unsigned short* W1ah = (unsigned short*)(ob + wofs);
  unsigned short* W1al = W1ah + 256 * 128;
  unsigned short* W1bh = (unsigned short*)(ob + wofs + 2 * 65536);
  unsigned short* W1bl = W1bh + 256 * 256;
  unsigned short* W2ah = (unsigned short*)(ob + wofs + 2 * 65536 + 2 * 131072);
  unsigned short* W2al = W2ah + 256 * 256;

  dim3 blk(256);
  dim3 gEdges((N_EDGES + 255) / 256);
  dim3 gAgg((N_NODES + 3) / 4);
  dim3 gGemm((N_NODES + 63) / 64);
  dim3 gW1((128 * 256 + 255) / 256);
  dim3 gW2((256 * 256 + 255) / 256);
  dim3 gXp((N_NODES * 128 + 255) / 256);

  // ---- CSR build + weight/x prep ----
  hipMemsetAsync(deg, 0, N_NODES * sizeof(int), stream);
  hist_k<<<gEdges, blk, 0, stream>>>(dstp, deg, N_EDGES);
  scan_k<<<1, 1024, 0, stream>>>(deg, rowStart, N_NODES);
  fill_k<<<gEdges, blk, 0, stream>>>(srcp, dstp, rowStart, sortedSrc, N_EDGES);
  xprep_k<<<gXp, blk, 0, stream>>>(x, xh, N_NODES * 128);
  wprep_k<<<gW1, blk, 0, stream>>>(W1a, W1ah, W1al, 128, 256);
  wprep_k<<<gW2, blk, 0, stream>>>(W1b, W1bh, W1bl, 256, 256);
  wprep_k<<<gW2, blk, 0, stream>>>(W2a, W2ah, W2al, 256, 256);

  // ---- Layer 1 ----
  agg_g16_k<128, true><<<gAgg, blk, 0, stream>>>(
      xh, x, nullptr, nullptr, eps1, rowStart, sortedSrc, C1h, C1l, N_NODES);
  gemm_wide_k<16, true, true><<<gGemm, blk, 0, stream>>>(
      C1h, C1l, W1ah, W1al, b1a, nullptr, T1h, T1l, N_NODES, 128);
  gemm_wide_k<16, true, true><<<gGemm, blk, 0, stream>>>(
      T1h, T1l, W1bh, W1bl, b1b, nullptr, Hh, Hl, N_NODES, 256);  // h as hilo

  // ---- Layer 2 ----
  agg_g16_k<256, false><<<gAgg, blk, 0, stream>>>(
      Hh, nullptr, Hh, Hl, eps2, rowStart, sortedSrc, C2h, C2l, N_NODES);
  gemm_wide_k<16, true, true><<<gGemm, blk, 0, stream>>>(
      C2h, C2l, W2ah, W2al, b2a, nullptr, T2h, T2l, N_NODES, 256);
  wprep_k<<<gW1, blk, 0, stream>>>(W2b, W2bh, W2bl, 256, 128);  // C2 dead now
  gemm_wide_k<8, false, false><<<gGemm, blk, 0, stream>>>(
      T2h, T2l, W2bh, W2bl, b2b, out, nullptr, nullptr, N_NODES, 256);
}